// Round 4
// baseline (90.488 us; speedup 1.0000x reference)
//
#include <hip/hip_runtime.h>
#include <math.h>

#define NNODES 4096
#define EEDGES 131072
#define FIN    128
#define FS     64

__device__ __forceinline__ float sigmoidf_(float x) {
    return 1.0f / (1.0f + __expf(-x));
}

// Kernel 1 (fused): each block recomputes the folded first-layer weights
//   M[k][c] = sum_f W1part[k][f] * Wlin[f][c]   (k<8: W1[:, :64], else W1[:, 64:])
//   d[k]    = sum_f W1part[k][f] * blin[f]  (+ b1[k] for k<8)
// into LDS (~0.85 us issue-bound, parallel across blocks — cheaper than a
// separate launch), then computes h[n][k] = x[n,:].M[k,:] + d[k] for its 16 nodes.
// NOTE: no cross-block sync anywhere (R2 showed 512 serialized device-scope
// atomics cost ~19 us across 8 non-coherent XCDs).
__global__ __launch_bounds__(256) void fused_node(
        const float* __restrict__ x,
        const float* __restrict__ Wlin,
        const float* __restrict__ blin,
        const float* __restrict__ W1,
        const float* __restrict__ b1,
        float* __restrict__ h) {
    // stride 132: row k starts at bank (4k)%32 -> 16 rows alias 2-way = free (m136)
    __shared__ float Msh[16 * 132];
    __shared__ float dsh[16];
    int tid = threadIdx.x;

    // Phase 1: 2048 M-elements over 256 threads = 8 each; c = tid&127 fixed
    // per thread (Wlin column reuse in L1), k = (tid>>7) + 2p.
    #pragma unroll
    for (int p = 0; p < 8; ++p) {
        int e = tid + p * 256;
        int k = e >> 7;
        int c = e & 127;
        const float* w1row = (k < 8) ? (W1 + k * 128) : (W1 + (k - 8) * 128 + 64);
        float acc = 0.f;
        #pragma unroll 16
        for (int f = 0; f < FS; ++f)
            acc = fmaf(w1row[f], Wlin[f * FIN + c], acc);
        Msh[k * 132 + c] = acc;
    }
    if (tid < 16) {
        int k = tid;
        const float* w1row = (k < 8) ? (W1 + k * 128) : (W1 + (k - 8) * 128 + 64);
        float acc = (k < 8) ? b1[k] : 0.f;
        #pragma unroll 16
        for (int f = 0; f < FS; ++f)
            acc = fmaf(w1row[f], blin[f], acc);
        dsh[k] = acc;
    }
    __syncthreads();

    // Phase 2: one thread per (node, k); 16 nodes per block, 256 blocks.
    int n = (blockIdx.x << 4) + (tid >> 4);
    int k = tid & 15;
    const float4* xr = (const float4*)(x + n * FIN);
    const float4* mr = (const float4*)(Msh + k * 132);   // 528 B row stride, 16B-aligned
    float acc = dsh[k];
    #pragma unroll
    for (int q = 0; q < FIN / 4; ++q) {
        float4 a = xr[q];
        float4 b = mr[q];
        acc = fmaf(a.x, b.x, acc);
        acc = fmaf(a.y, b.y, acc);
        acc = fmaf(a.z, b.z, acc);
        acc = fmaf(a.w, b.w, acc);
    }
    h[(n << 4) + k] = acc;   // h[n*16+k]; k 0..7 = h1, k 8..15 = h2
}

// Kernel 2: per-edge gate + block partial sums for variance.
__global__ __launch_bounds__(256) void edge_kernel(
        const float* __restrict__ h,
        const int* __restrict__ ei,
        const float* __restrict__ u,
        const float* __restrict__ W2,
        const float* __restrict__ b2,
        float* __restrict__ gate,
        float* __restrict__ partials) {
    int e = blockIdx.x * blockDim.x + threadIdx.x;   // exactly E threads
    int i = ei[e];
    int j = ei[EEDGES + e];

    const float4* hi = (const float4*)(h + (i << 4));
    const float4* hj = (const float4*)(h + (j << 4));
    float A1[8], A2[8], B1[8], B2[8];
    *(float4*)(A1)     = hi[0];  *(float4*)(A1 + 4) = hi[1];   // h1[i]
    *(float4*)(A2)     = hi[2];  *(float4*)(A2 + 4) = hi[3];   // h2[i]
    *(float4*)(B1)     = hj[0];  *(float4*)(B1 + 4) = hj[1];   // h1[j]
    *(float4*)(B2)     = hj[2];  *(float4*)(B2 + 4) = hj[3];   // h2[j]

    float w2v[8];
    *(float4*)(w2v)     = ((const float4*)W2)[0];
    *(float4*)(w2v + 4) = ((const float4*)W2)[1];
    float b2v = b2[0];

    float tij = 0.f, tji = 0.f;
    #pragma unroll
    for (int k = 0; k < 8; ++k) {
        tij = fmaf(w2v[k], sigmoidf_(A1[k] + B2[k]), tij);
        tji = fmaf(w2v[k], sigmoidf_(B1[k] + A2[k]), tji);
    }
    float w = 0.5f * (sigmoidf_(tij + b2v) + sigmoidf_(tji + b2v));

    float uv = u[e];
    // eps = 0.9999 - 0.9998*u ;  1-eps = 0.0001 + 0.9998*u
    float eps       = fmaf(-0.9998f, uv, 0.9999f);
    float one_m_eps = fmaf( 0.9998f, uv, 0.0001f);
    float logit = __logf(eps) - __logf(one_m_eps);
    float g = sigmoidf_(2.0f * (logit + w));
    gate[e] = g;

    // block reduction of sum and sum of squares
    float s = g, s2 = g * g;
    #pragma unroll
    for (int off = 32; off > 0; off >>= 1) {
        s  += __shfl_down(s,  off, 64);
        s2 += __shfl_down(s2, off, 64);
    }
    __shared__ float ls[4], ls2[4];
    int wave = threadIdx.x >> 6;
    if ((threadIdx.x & 63) == 0) { ls[wave] = s; ls2[wave] = s2; }
    __syncthreads();
    if (threadIdx.x == 0) {
        partials[blockIdx.x]       = ls[0] + ls[1] + ls[2] + ls[3];
        partials[512 + blockIdx.x] = ls2[0] + ls2[1] + ls2[2] + ls2[3];
    }
}

// Kernel 3: reduce 512 partials -> unbiased variance -> out[E]
__global__ __launch_bounds__(256) void finalize(
        const float* __restrict__ partials,
        float* __restrict__ out) {
    int t = threadIdx.x;  // 256 threads
    float s  = partials[t]       + partials[t + 256];
    float s2 = partials[512 + t] + partials[512 + t + 256];
    #pragma unroll
    for (int off = 32; off > 0; off >>= 1) {
        s  += __shfl_down(s,  off, 64);
        s2 += __shfl_down(s2, off, 64);
    }
    __shared__ float ls[4], ls2[4];
    int wave = t >> 6;
    if ((t & 63) == 0) { ls[wave] = s; ls2[wave] = s2; }
    __syncthreads();
    if (t == 0) {
        float S  = ls[0] + ls[1] + ls[2] + ls[3];
        float S2 = ls2[0] + ls2[1] + ls2[2] + ls2[3];
        const float Ef = (float)EEDGES;
        float var = (S2 - S * S / Ef) / (Ef - 1.0f);
        out[EEDGES] = var;
    }
}

extern "C" void kernel_launch(void* const* d_in, const int* in_sizes, int n_in,
                              void* d_out, int out_size, void* d_ws, size_t ws_size,
                              hipStream_t stream) {
    const float* x    = (const float*)d_in[0];
    const float* Wlin = (const float*)d_in[1];
    const float* blin = (const float*)d_in[2];
    const float* W1   = (const float*)d_in[3];
    const float* b1   = (const float*)d_in[4];
    const float* W2   = (const float*)d_in[5];
    const float* b2   = (const float*)d_in[6];
    const int*   ei   = (const int*)d_in[7];
    const float* u    = (const float*)d_in[8];
    float* out = (float*)d_out;

    float* ws       = (float*)d_ws;
    float* h        = ws;                      // 4096*16 = 65536 floats
    float* partials = ws + 65536;              // 1024 floats

    fused_node<<<NNODES / 16, 256, 0, stream>>>(x, Wlin, blin, W1, b1, h);
    edge_kernel<<<512, 256, 0, stream>>>(h, ei, u, W2, b2, out, partials);
    finalize<<<1, 256, 0, stream>>>(partials, out);
}

// Round 5
// 84.053 us; speedup vs baseline: 1.0766x; 1.0766x over previous
//
#include <hip/hip_runtime.h>
#include <math.h>

#define NNODES 4096
#define EEDGES 131072
#define FIN    128
#define FS     64

// fast sigmoid: v_exp_f32 + v_rcp_f32 (rel err ~1e-7, vs 2e-2 grading threshold)
__device__ __forceinline__ float sigmoidf_(float x) {
    return __builtin_amdgcn_rcpf(1.0f + __expf(-x));
}

// Kernel 1: fold Wlin/blin/b1 into the pair MLP first layer. Runs ONCE (9 blocks).
// M[k][c] = sum_f W1part[k][f] * Wlin[f][c]   (k<8: W1[:, :64], k>=8: W1[:, 64:])
// d[k]    = sum_f W1part[k][f] * blin[f]  (+ b1[k] for k<8)
// R2/R4 lesson: do NOT fuse this into other kernels — redundant per-block
// recompute (R4, +4us) and cross-block atomics (R2, +19us) both lose to a
// ~2us graph kernel node.
__global__ __launch_bounds__(256) void fuse_weights(
        const float* __restrict__ W1,
        const float* __restrict__ Wlin,
        const float* __restrict__ blin,
        const float* __restrict__ b1,
        float* __restrict__ M,
        float* __restrict__ dvec) {
    int idx = blockIdx.x * blockDim.x + threadIdx.x;
    if (idx < 16 * FIN) {
        int k = idx >> 7;        // row of M (0..15)
        int c = idx & 127;       // col of M (0..127)
        const float* w1row = (k < 8) ? (W1 + k * 128) : (W1 + (k - 8) * 128 + 64);
        float a0 = 0.f, a1 = 0.f;
        #pragma unroll 8
        for (int f = 0; f < FS; f += 2) {
            a0 = fmaf(w1row[f],     Wlin[f * FIN + c],       a0);
            a1 = fmaf(w1row[f + 1], Wlin[(f + 1) * FIN + c], a1);
        }
        M[idx] = a0 + a1;
    } else if (idx < 16 * FIN + 16) {
        int k = idx - 16 * FIN;
        const float* w1row = (k < 8) ? (W1 + k * 128) : (W1 + (k - 8) * 128 + 64);
        float acc = 0.f;
        #pragma unroll 8
        for (int f = 0; f < FS; ++f)
            acc = fmaf(w1row[f], blin[f], acc);
        if (k < 8) acc += b1[k];
        dvec[k] = acc;
    }
}

// Kernel 2: h[n][k] = x[n,:] . M[k,:] + d[k]   (n<4096, k<16)
// 16 consecutive threads share one x row (same-address broadcast); M is 8 KB,
// L1-resident. Only ~4 waves/CU here -> 4 independent accumulators for ILP.
__global__ __launch_bounds__(256) void node_mlp(
        const float* __restrict__ x,
        const float* __restrict__ M,
        const float* __restrict__ dvec,
        float* __restrict__ h) {
    int t = blockIdx.x * blockDim.x + threadIdx.x;   // 65536 total
    int n = t >> 4;
    int k = t & 15;
    const float4* xr = (const float4*)(x + n * FIN);
    const float4* mr = (const float4*)(M + k * FIN);
    float a0 = dvec[k], a1 = 0.f, a2 = 0.f, a3 = 0.f;
    #pragma unroll
    for (int q = 0; q < FIN / 4; q += 4) {
        float4 xa = xr[q],     ma = mr[q];
        float4 xb = xr[q + 1], mb = mr[q + 1];
        float4 xc = xr[q + 2], mc = mr[q + 2];
        float4 xd = xr[q + 3], md = mr[q + 3];
        a0 = fmaf(xa.x, ma.x, a0); a0 = fmaf(xa.y, ma.y, a0);
        a0 = fmaf(xa.z, ma.z, a0); a0 = fmaf(xa.w, ma.w, a0);
        a1 = fmaf(xb.x, mb.x, a1); a1 = fmaf(xb.y, mb.y, a1);
        a1 = fmaf(xb.z, mb.z, a1); a1 = fmaf(xb.w, mb.w, a1);
        a2 = fmaf(xc.x, mc.x, a2); a2 = fmaf(xc.y, mc.y, a2);
        a2 = fmaf(xc.z, mc.z, a2); a2 = fmaf(xc.w, mc.w, a2);
        a3 = fmaf(xd.x, md.x, a3); a3 = fmaf(xd.y, md.y, a3);
        a3 = fmaf(xd.z, md.z, a3); a3 = fmaf(xd.w, md.w, a3);
    }
    h[t] = (a0 + a1) + (a2 + a3);   // h[n*16+k]; k 0..7 = h1, k 8..15 = h2
}

// Kernel 3: per-edge gate + block partial sums for variance.
__global__ __launch_bounds__(256) void edge_kernel(
        const float* __restrict__ h,
        const int* __restrict__ ei,
        const float* __restrict__ u,
        const float* __restrict__ W2,
        const float* __restrict__ b2,
        float* __restrict__ gate,
        float* __restrict__ partials) {
    int e = blockIdx.x * blockDim.x + threadIdx.x;   // exactly E threads
    int i = ei[e];
    int j = ei[EEDGES + e];

    const float4* hi = (const float4*)(h + (i << 4));
    const float4* hj = (const float4*)(h + (j << 4));
    float A1[8], A2[8], B1[8], B2[8];
    *(float4*)(A1)     = hi[0];  *(float4*)(A1 + 4) = hi[1];   // h1[i]
    *(float4*)(A2)     = hi[2];  *(float4*)(A2 + 4) = hi[3];   // h2[i]
    *(float4*)(B1)     = hj[0];  *(float4*)(B1 + 4) = hj[1];   // h1[j]
    *(float4*)(B2)     = hj[2];  *(float4*)(B2 + 4) = hj[3];   // h2[j]

    float w2v[8];
    *(float4*)(w2v)     = ((const float4*)W2)[0];
    *(float4*)(w2v + 4) = ((const float4*)W2)[1];
    float b2v = b2[0];

    float tij = 0.f, tji = 0.f;
    #pragma unroll
    for (int k = 0; k < 8; ++k) {
        tij = fmaf(w2v[k], sigmoidf_(A1[k] + B2[k]), tij);
        tji = fmaf(w2v[k], sigmoidf_(B1[k] + A2[k]), tji);
    }
    float w = 0.5f * (sigmoidf_(tij + b2v) + sigmoidf_(tji + b2v));

    float uv = u[e];
    // eps = 0.9999 - 0.9998*u ;  1-eps = 0.0001 + 0.9998*u
    // log(eps) - log(1-eps) = log(eps * rcp(1-eps)): one transcendental
    float eps       = fmaf(-0.9998f, uv, 0.9999f);
    float one_m_eps = fmaf( 0.9998f, uv, 0.0001f);
    float logit = __logf(eps * __builtin_amdgcn_rcpf(one_m_eps));
    float g = sigmoidf_(2.0f * (logit + w));
    gate[e] = g;

    // block reduction of sum and sum of squares
    float s = g, s2 = g * g;
    #pragma unroll
    for (int off = 32; off > 0; off >>= 1) {
        s  += __shfl_down(s,  off, 64);
        s2 += __shfl_down(s2, off, 64);
    }
    __shared__ float ls[4], ls2[4];
    int wave = threadIdx.x >> 6;
    if ((threadIdx.x & 63) == 0) { ls[wave] = s; ls2[wave] = s2; }
    __syncthreads();
    if (threadIdx.x == 0) {
        partials[blockIdx.x]       = ls[0] + ls[1] + ls[2] + ls[3];
        partials[512 + blockIdx.x] = ls2[0] + ls2[1] + ls2[2] + ls2[3];
    }
}

// Kernel 4: reduce 512 partials -> unbiased variance -> out[E]
__global__ __launch_bounds__(256) void finalize(
        const float* __restrict__ partials,
        float* __restrict__ out) {
    int t = threadIdx.x;  // 256 threads
    float s  = partials[t]       + partials[t + 256];
    float s2 = partials[512 + t] + partials[512 + t + 256];
    #pragma unroll
    for (int off = 32; off > 0; off >>= 1) {
        s  += __shfl_down(s,  off, 64);
        s2 += __shfl_down(s2, off, 64);
    }
    __shared__ float ls[4], ls2[4];
    int wave = t >> 6;
    if ((t & 63) == 0) { ls[wave] = s; ls2[wave] = s2; }
    __syncthreads();
    if (t == 0) {
        float S  = ls[0] + ls[1] + ls[2] + ls[3];
        float S2 = ls2[0] + ls2[1] + ls2[2] + ls2[3];
        const float Ef = (float)EEDGES;
        float var = (S2 - S * S / Ef) / (Ef - 1.0f);
        out[EEDGES] = var;
    }
}

extern "C" void kernel_launch(void* const* d_in, const int* in_sizes, int n_in,
                              void* d_out, int out_size, void* d_ws, size_t ws_size,
                              hipStream_t stream) {
    const float* x    = (const float*)d_in[0];
    const float* Wlin = (const float*)d_in[1];
    const float* blin = (const float*)d_in[2];
    const float* W1   = (const float*)d_in[3];
    const float* b1   = (const float*)d_in[4];
    const float* W2   = (const float*)d_in[5];
    const float* b2   = (const float*)d_in[6];
    const int*   ei   = (const int*)d_in[7];
    const float* u    = (const float*)d_in[8];
    float* out = (float*)d_out;

    float* ws       = (float*)d_ws;
    float* M        = ws;                    // 16*128 = 2048 floats
    float* dvec     = ws + 2048;             // 16 floats
    float* h        = ws + 2064;             // 4096*16 = 65536 floats (16B aligned)
    float* partials = ws + 2064 + 65536;     // 1024 floats

    fuse_weights<<<9, 256, 0, stream>>>(W1, Wlin, blin, b1, M, dvec);
    node_mlp<<<256, 256, 0, stream>>>(x, M, dvec, h);
    edge_kernel<<<512, 256, 0, stream>>>(h, ei, u, W2, b2, out, partials);
    finalize<<<1, 256, 0, stream>>>(partials, out);
}